// Round 26
// baseline (33.398 us; speedup 1.0000x reference)
//
#include <hip/hip_runtime.h>
#include <hip/hip_bf16.h>
#include <cmath>

#define NTOK 4096

typedef float        f32x16 __attribute__((ext_vector_type(16)));
typedef short        s16x8  __attribute__((ext_vector_type(8)));
typedef unsigned int u32x4  __attribute__((ext_vector_type(4)));

__device__ __forceinline__ unsigned short f2bf(float f) {
    __hip_bfloat16 h = __float2bfloat16(f);
    return *reinterpret_cast<unsigned short*>(&h);
}
__device__ __forceinline__ float bf2f(unsigned short u) {
    __hip_bfloat16 h = *reinterpret_cast<__hip_bfloat16*>(&u);
    return __bfloat162float(h);
}
// packed f32x2 -> bf16x2 via HIP intrinsic (lowers to v_cvt_pk_bf16_f32)
__device__ __forceinline__ unsigned pk2(float a, float b) {
    __hip_bfloat162 h = __float22bfloat162_rn(make_float2(a, b));
    return *reinterpret_cast<unsigned*>(&h);
}

// ---------------------------------------------------------------------------
// Kernel 1: QKV projection via MFMA, ROW-TILE-SPLIT grid.  R25 (grid 128,
// 3 tiles per wave) ran at 0.5 waves/SIMD -- one long latency chain per
// wave.  Now blk = tile*128 + group: wave = ONE 32-row tile x 32 voxels,
// grid 384 = 1.5 waves/SIMD, per-wave loads 56 -> 40 (32 x-dwords + 8
// W-float4), 4 MFMA.  Same verified fragment layouts; same store formats:
// qt2/kt2[b][i][16]=[hi|lo] (q log2e-scaled), vt[b][i/16][c][sigma(i%16)].
// ---------------------------------------------------------------------------
__global__ __launch_bounds__(256, 4)
void qkv_kernel(const float* __restrict__ x,
                const float* __restrict__ Wq, const float* __restrict__ bq,
                const float* __restrict__ Wk, const float* __restrict__ bk,
                const float* __restrict__ Wv, const float* __restrict__ bv,
                unsigned short* __restrict__ qt2, unsigned short* __restrict__ kt2,
                unsigned short* __restrict__ vt)
{
    const int t    = threadIdx.x;
    const int l    = t & 63;
    const int wv   = t >> 6;            // 0..3: col-tile within block
    const int lo31 = l & 31;
    const int h    = l >> 5;
    const int blk  = blockIdx.x;        // 0..383
    const int tile = blk >> 7;          // 0..2 (row-tile)
    const int grp  = blk & 127;         // voxel group
    const int b    = grp >> 5;          // 0..3
    const int i    = ((grp & 31) << 7) + (wv << 5) + lo31;   // 0..4095

    // ---- B-frags: x_bf16[k = 16ks+8h .. +8][vox=i], 4 K-steps ----
    const float* xb = x + ((size_t)b * 64) * NTOK + i;
    s16x8 B0, B1, B2, B3;
    #define MAKE_B(Bv, ks) do {                                               \
        const float* src = xb + (size_t)((ks) * 16 + 8 * h) * NTOK;           \
        float f0 = src[0];                  float f1 = src[NTOK];             \
        float f2 = src[2 * (size_t)NTOK];   float f3 = src[3 * (size_t)NTOK]; \
        float f4 = src[4 * (size_t)NTOK];   float f5 = src[5 * (size_t)NTOK]; \
        float f6 = src[6 * (size_t)NTOK];   float f7 = src[7 * (size_t)NTOK]; \
        u32x4 p;                                                              \
        p.x = pk2(f0, f1); p.y = pk2(f2, f3);                                 \
        p.z = pk2(f4, f5); p.w = pk2(f6, f7);                                 \
        Bv = __builtin_bit_cast(s16x8, p);                                    \
    } while (0)
    MAKE_B(B0, 0); MAKE_B(B1, 1); MAKE_B(B2, 2); MAKE_B(B3, 3);

    // ---- this tile's A-frags from W (L2-hot), accumulate over K ----
    f32x16 C;
    #pragma unroll
    for (int r = 0; r < 16; r++) C[r] = 0.f;

    const int row = tile * 32 + lo31;
    const bool act = (row < 80);
    const float* wrow = (row < 8)  ? (Wq + row * 64)
                      : (row < 16) ? (Wk + (row - 8) * 64)
                      : act        ? (Wv + (row - 16) * 64)
                                   : Wq;              // inert, loads guarded
    #pragma unroll
    for (int ks = 0; ks < 4; ks++) {
        u32x4 p;
        if (act) {
            const float4 f0 = ((const float4*)(wrow + ks * 16 + 8 * h))[0];
            const float4 f1 = ((const float4*)(wrow + ks * 16 + 8 * h))[1];
            p.x = pk2(f0.x, f0.y); p.y = pk2(f0.z, f0.w);
            p.z = pk2(f1.x, f1.y); p.w = pk2(f1.z, f1.w);
        } else { p.x = 0; p.y = 0; p.z = 0; p.w = 0; }
        const s16x8 A = __builtin_bit_cast(s16x8, p);
        const s16x8 Bk = (ks == 0) ? B0 : (ks == 1) ? B1 : (ks == 2) ? B2 : B3;
        C = __builtin_amdgcn_mfma_f32_32x32x16_bf16(A, Bk, C, 0, 0, 0);
    }

    // ---- epilogue: store this tile's rows in the existing formats ----
    const size_t rowq = ((size_t)b * NTOK + i) * 16;
    const int jl   = i & 15;
    const int slot = (jl & 3) | ((jl & 4) << 1) | ((jl & 8) >> 1);  // swap b2<->b3
    const size_t vbase = ((size_t)b * 256 + (i >> 4)) * 1024 + slot;

    #pragma unroll
    for (int r = 0; r < 16; r++) {
        const int grow = tile * 32 + (r & 3) + 8 * (r >> 2) + 4 * h;
        const float cval = C[r];
        if (grow < 8) {
            const float fin = (cval + bq[grow]) * 1.4426950408889634f;
            const unsigned short hu = f2bf(fin);
            qt2[rowq + grow]     = hu;
            qt2[rowq + 8 + grow] = f2bf(fin - bf2f(hu));
        } else if (grow < 16) {
            const int o = grow - 8;
            const float fin = cval + bk[o];
            const unsigned short hu = f2bf(fin);
            kt2[rowq + o]     = hu;
            kt2[rowq + 8 + o] = f2bf(fin - bf2f(hu));
        } else if (grow < 80) {
            const int c = grow - 16;
            vt[vbase + (size_t)c * 16] = f2bf(cval + bv[c]);
        }
    }
}

// ---------------------------------------------------------------------------
// Kernel 2: fused flash attention with WAVE-PAIRING (champion, verbatim).
// ---------------------------------------------------------------------------
__global__ __launch_bounds__(1024)
void attn_kernel(const unsigned short* __restrict__ qt2,
                 const unsigned short* __restrict__ kt2,
                 const unsigned short* __restrict__ vt,
                 const float* __restrict__ x,
                 const float* __restrict__ gamma,
                 float* __restrict__ out)
{
    __shared__ float slds[4][64][64];   // merge slots [c][q 0..63], 64 KB
    __shared__ float sldl[4][64];       // l per slot

    const int t    = threadIdx.x;       // 0..1023
    const int l    = t & 63;
    const int wv   = t >> 6;            // 0..15
    const int qt   = wv & 1;            // q-tile of this wave (pairing key)
    const int u    = wv >> 1;           // 0..7 j-range id (shared by pair)
    const int lo31 = l & 31;
    const int h    = l >> 5;
    const int w     = blockIdx.x;
    const int b     = w >> 6;
    const int qbase = (w & 63) << 6;    // 64 q per block
    const int j0    = u << 9;           // 512 j per wave

    const unsigned short* qrow =
        qt2 + ((size_t)b * NTOK + qbase + qt * 32 + lo31) * 16;
    s16x8 qB1 = *(const s16x8*)qrow;
    s16x8 qB2;
    if (h == 0) qB2 = *(const s16x8*)(qrow + 8);
    else        { u32x4 z = {0,0,0,0}; qB2 = __builtin_bit_cast(s16x8, z); }

    const unsigned short* kb  = kt2 + (size_t)b * NTOK * 16 + (size_t)h * 8;
    const unsigned short* vbA = vt + (size_t)b * NTOK * 64 + (size_t)lo31 * 16 + 8 * h;
    const unsigned short* vbB = vbA + 512;

    f32x16 accA, accB;
    #pragma unroll
    for (int r = 0; r < 16; r++) { accA[r] = 0.f; accB[r] = 0.f; }
    float lsum = 0.f;

    s16x8 K[2], V00[2], V01[2], V10[2], V11[2];

    #define LOADSET(s_, a_) do {                                              \
        K[s_]   = *(const s16x8*)(kb + (size_t)(j0 + ((a_) << 5) + lo31) * 16);  \
        V00[s_] = *(const s16x8*)(vbA + (size_t)((j0 >> 4) + ((a_) << 1)) * 1024);     \
        V01[s_] = *(const s16x8*)(vbA + (size_t)((j0 >> 4) + ((a_) << 1) + 1) * 1024); \
        V10[s_] = *(const s16x8*)(vbB + (size_t)((j0 >> 4) + ((a_) << 1)) * 1024);     \
        V11[s_] = *(const s16x8*)(vbB + (size_t)((j0 >> 4) + ((a_) << 1) + 1) * 1024); \
    } while (0)

    LOADSET(0, 0);

    #pragma unroll
    for (int it = 0; it < 16; ++it) {
        const int cu = it & 1;
        const int nx = it + 1;
        LOADSET(cu ^ 1, (nx < 16) ? nx : 0);   // issue next-chunk loads first

        f32x16 s;
        #pragma unroll
        for (int r = 0; r < 16; r++) s[r] = 0.f;
        s = __builtin_amdgcn_mfma_f32_32x32x16_bf16(K[cu], qB1, s, 0, 0, 0);
        s = __builtin_amdgcn_mfma_f32_32x32x16_bf16(K[cu], qB2, s, 0, 0, 0);

        // ---- p = exp2(s) raw (no max needed: CQ=8 keeps |s| small) ----
        #pragma unroll
        for (int r = 0; r < 16; r++) s[r] = __builtin_amdgcn_exp2f(s[r]);

        lsum += ((s[0]+s[1])+(s[2]+s[3])) + ((s[4]+s[5])+(s[6]+s[7]))
              + ((s[8]+s[9])+(s[10]+s[11])) + ((s[12]+s[13])+(s[14]+s[15]));

        // ---- P^T -> B-frags: direct repack of own registers ----
        u32x4 wa, wc;
        wa.x = pk2(s[0], s[1]);   wa.y = pk2(s[2], s[3]);
        wa.z = pk2(s[4], s[5]);   wa.w = pk2(s[6], s[7]);
        wc.x = pk2(s[8], s[9]);   wc.y = pk2(s[10], s[11]);
        wc.z = pk2(s[12], s[13]); wc.w = pk2(s[14], s[15]);
        s16x8 pf0 = __builtin_bit_cast(s16x8, wa);
        s16x8 pf1 = __builtin_bit_cast(s16x8, wc);

        __builtin_amdgcn_s_setprio(1);
        accA = __builtin_amdgcn_mfma_f32_32x32x16_bf16(V00[cu], pf0, accA, 0, 0, 0);
        accA = __builtin_amdgcn_mfma_f32_32x32x16_bf16(V01[cu], pf1, accA, 0, 0, 0);
        accB = __builtin_amdgcn_mfma_f32_32x32x16_bf16(V10[cu], pf0, accB, 0, 0, 0);
        accB = __builtin_amdgcn_mfma_f32_32x32x16_bf16(V11[cu], pf1, accB, 0, 0, 0);
        __builtin_amdgcn_s_setprio(0);
    }

    lsum += __shfl_xor(lsum, 32);

    #define WR_SLOT(sidx) do {                                                \
        const int s_ = (sidx);                                                \
        _Pragma("unroll")                                                     \
        for (int r = 0; r < 16; r++) {                                        \
            const int c_ = (r & 3) + 8 * (r >> 2) + 4 * h;                    \
            slds[s_][c_][qt * 32 + lo31]      = accA[r];                      \
            slds[s_][c_ + 32][qt * 32 + lo31] = accB[r];                      \
        }                                                                     \
        if (h == 0) sldl[s_][qt * 32 + lo31] = lsum;                          \
    } while (0)

    #define MRG_SLOT(sidx) do {                                               \
        const int s_ = (sidx);                                                \
        _Pragma("unroll")                                                     \
        for (int r = 0; r < 16; r++) {                                        \
            const int c_ = (r & 3) + 8 * (r >> 2) + 4 * h;                    \
            accA[r] += slds[s_][c_][qt * 32 + lo31];                          \
            accB[r] += slds[s_][c_ + 32][qt * 32 + lo31];                     \
        }                                                                     \
        lsum += sldl[s_][qt * 32 + lo31];                                     \
    } while (0)

    if (u >= 4) WR_SLOT(u - 4);
    __syncthreads();
    if (u < 4) MRG_SLOT(u);
    __syncthreads();
    if (u == 2 || u == 3) WR_SLOT(u - 2);
    __syncthreads();
    if (u < 2) MRG_SLOT(u);
    __syncthreads();
    if (u == 1) WR_SLOT(0);
    __syncthreads();
    if (u == 0) { MRG_SLOT(0); WR_SLOT(0); }
    __syncthreads();

    // ---- fused epilogue: out = gamma*acc/L + x, all 1024 threads ----
    const int c  = t >> 4;              // 0..63
    const int q4 = (t & 15) << 2;       // 0,4,..,60
    const float g = gamma[0];
    const float4 a4 = *(const float4*)&slds[0][c][q4];
    const float g0 = g / sldl[0][q4 + 0];
    const float g1 = g / sldl[0][q4 + 1];
    const float g2 = g / sldl[0][q4 + 2];
    const float g3 = g / sldl[0][q4 + 3];
    const size_t off = (((size_t)b * 64 + c) << 12) + qbase + q4;
    const float4 xv4 = *(const float4*)(x + off);
    float4 o;
    o.x = a4.x * g0 + xv4.x;
    o.y = a4.y * g1 + xv4.y;
    o.z = a4.z * g2 + xv4.z;
    o.w = a4.w * g3 + xv4.w;
    *(float4*)(out + off) = o;
}

// ---------------------------------------------------------------------------
extern "C" void kernel_launch(void* const* d_in, const int* in_sizes, int n_in,
                              void* d_out, int out_size, void* d_ws, size_t ws_size,
                              hipStream_t stream) {
    const float* x     = (const float*)d_in[0];
    const float* Wq    = (const float*)d_in[1];
    const float* bq    = (const float*)d_in[2];
    const float* Wk    = (const float*)d_in[3];
    const float* bk    = (const float*)d_in[4];
    const float* Wv    = (const float*)d_in[5];
    const float* bv    = (const float*)d_in[6];
    const float* gamma = (const float*)d_in[7];
    float* out = (float*)d_out;

    unsigned short* qt2 = (unsigned short*)d_ws;            // 4*4096*16 bf16
    unsigned short* kt2 = qt2 + (size_t)4 * NTOK * 16;      // 4*4096*16 bf16
    unsigned short* vt  = kt2 + (size_t)4 * NTOK * 16;      // 4*4096*64 bf16 (tiled+permuted)

    qkv_kernel<<<384, 256, 0, stream>>>(x, Wq, bq, Wk, bk, Wv, bv, qt2, kt2, vt);
    attn_kernel<<<256, 1024, 0, stream>>>(qt2, kt2, vt, x, gamma, out);
}

// Round 27
// 31.305 us; speedup vs baseline: 1.0669x; 1.0669x over previous
//
#include <hip/hip_runtime.h>
#include <hip/hip_bf16.h>
#include <cmath>

#define NTOK 4096

typedef float        f32x16 __attribute__((ext_vector_type(16)));
typedef short        s16x8  __attribute__((ext_vector_type(8)));
typedef unsigned int u32x4  __attribute__((ext_vector_type(4)));

__device__ __forceinline__ unsigned short f2bf(float f) {
    __hip_bfloat16 h = __float2bfloat16(f);
    return *reinterpret_cast<unsigned short*>(&h);
}
__device__ __forceinline__ float bf2f(unsigned short u) {
    __hip_bfloat16 h = *reinterpret_cast<__hip_bfloat16*>(&u);
    return __bfloat162float(h);
}
// packed f32x2 -> bf16x2 via HIP intrinsic (lowers to v_cvt_pk_bf16_f32)
__device__ __forceinline__ unsigned pk2(float a, float b) {
    __hip_bfloat162 h = __float22bfloat162_rn(make_float2(a, b));
    return *reinterpret_cast<unsigned*>(&h);
}

// ---------------------------------------------------------------------------
// Kernel 1: QKV projection via MFMA (R25 champion, restored verbatim —
// session best 31.31 us).  Grid 128 x 256 thr; block = 4 waves x 32 voxels;
// each wave computes ALL 3 row-tiles (96 rows padded, zero-guarded) for its
// 32 voxels: 56 independent loads (32 x-dwords + 24 W-float4), 12 MFMA.
// R26's row-tile-split (grid 384) tripled redundant x loads and regressed —
// unique-work latency, not occupancy, is the binding constraint here.
// Fragment layouts are the attn-verified mappings.  Stores byte-identical
// formats: qt2/kt2[b][i][16]=[hi|lo] (q log2e-scaled),
// vt[b][i/16][c][sigma(i%16)], sigma = swap b2<->b3.
// ---------------------------------------------------------------------------
__global__ __launch_bounds__(256, 4)
void qkv_kernel(const float* __restrict__ x,
                const float* __restrict__ Wq, const float* __restrict__ bq,
                const float* __restrict__ Wk, const float* __restrict__ bk,
                const float* __restrict__ Wv, const float* __restrict__ bv,
                unsigned short* __restrict__ qt2, unsigned short* __restrict__ kt2,
                unsigned short* __restrict__ vt)
{
    const int t    = threadIdx.x;
    const int l    = t & 63;
    const int wv   = t >> 6;            // 0..3: col-tile within block
    const int lo31 = l & 31;
    const int h    = l >> 5;
    const int blk  = blockIdx.x;        // 0..127
    const int b    = blk >> 5;          // 0..3
    const int i    = ((blk & 31) << 7) + (wv << 5) + lo31;   // 0..4095

    // ---- B-frags: x_bf16[k = 16ks+8h .. +8][vox=i], 4 K-steps ----
    const float* xb = x + ((size_t)b * 64) * NTOK + i;
    s16x8 B0, B1, B2, B3;
    #define MAKE_B(Bv, ks) do {                                               \
        const float* src = xb + (size_t)((ks) * 16 + 8 * h) * NTOK;           \
        float f0 = src[0];                  float f1 = src[NTOK];             \
        float f2 = src[2 * (size_t)NTOK];   float f3 = src[3 * (size_t)NTOK]; \
        float f4 = src[4 * (size_t)NTOK];   float f5 = src[5 * (size_t)NTOK]; \
        float f6 = src[6 * (size_t)NTOK];   float f7 = src[7 * (size_t)NTOK]; \
        u32x4 p;                                                              \
        p.x = pk2(f0, f1); p.y = pk2(f2, f3);                                 \
        p.z = pk2(f4, f5); p.w = pk2(f6, f7);                                 \
        Bv = __builtin_bit_cast(s16x8, p);                                    \
    } while (0)
    MAKE_B(B0, 0); MAKE_B(B1, 1); MAKE_B(B2, 2); MAKE_B(B3, 3);

    // ---- 3 row-tiles: A-frags from W (L2-hot), accumulate over K ----
    f32x16 C0, C1, C2;
    #pragma unroll
    for (int r = 0; r < 16; r++) { C0[r] = 0.f; C1[r] = 0.f; C2[r] = 0.f; }

    #pragma unroll
    for (int tile = 0; tile < 3; tile++) {
        const int row = tile * 32 + lo31;
        const bool act = (row < 80);
        const float* wrow = (row < 8)  ? (Wq + row * 64)
                          : (row < 16) ? (Wk + (row - 8) * 64)
                          : act        ? (Wv + (row - 16) * 64)
                                       : Wq;              // inert, loads guarded
        #pragma unroll
        for (int ks = 0; ks < 4; ks++) {
            u32x4 p;
            if (act) {
                const float4 f0 = ((const float4*)(wrow + ks * 16 + 8 * h))[0];
                const float4 f1 = ((const float4*)(wrow + ks * 16 + 8 * h))[1];
                p.x = pk2(f0.x, f0.y); p.y = pk2(f0.z, f0.w);
                p.z = pk2(f1.x, f1.y); p.w = pk2(f1.z, f1.w);
            } else { p.x = 0; p.y = 0; p.z = 0; p.w = 0; }
            const s16x8 A = __builtin_bit_cast(s16x8, p);
            const s16x8 Bk = (ks == 0) ? B0 : (ks == 1) ? B1 : (ks == 2) ? B2 : B3;
            if (tile == 0)      C0 = __builtin_amdgcn_mfma_f32_32x32x16_bf16(A, Bk, C0, 0, 0, 0);
            else if (tile == 1) C1 = __builtin_amdgcn_mfma_f32_32x32x16_bf16(A, Bk, C1, 0, 0, 0);
            else                C2 = __builtin_amdgcn_mfma_f32_32x32x16_bf16(A, Bk, C2, 0, 0, 0);
        }
    }

    // ---- epilogue: store in the existing formats ----
    const size_t rowq = ((size_t)b * NTOK + i) * 16;
    const int jl   = i & 15;
    const int slot = (jl & 3) | ((jl & 4) << 1) | ((jl & 8) >> 1);  // swap b2<->b3
    const size_t vbase = ((size_t)b * 256 + (i >> 4)) * 1024 + slot;

    #pragma unroll
    for (int tile = 0; tile < 3; tile++) {
        #pragma unroll
        for (int r = 0; r < 16; r++) {
            const int grow = tile * 32 + (r & 3) + 8 * (r >> 2) + 4 * h;
            const float cval = (tile == 0) ? C0[r] : (tile == 1) ? C1[r] : C2[r];
            if (grow < 8) {
                const float fin = (cval + bq[grow]) * 1.4426950408889634f;
                const unsigned short hu = f2bf(fin);
                qt2[rowq + grow]     = hu;
                qt2[rowq + 8 + grow] = f2bf(fin - bf2f(hu));
            } else if (grow < 16) {
                const int o = grow - 8;
                const float fin = cval + bk[o];
                const unsigned short hu = f2bf(fin);
                kt2[rowq + o]     = hu;
                kt2[rowq + 8 + o] = f2bf(fin - bf2f(hu));
            } else if (grow < 80) {
                const int c = grow - 16;
                vt[vbase + (size_t)c * 16] = f2bf(cval + bv[c]);
            }
        }
    }
}

// ---------------------------------------------------------------------------
// Kernel 2: fused flash attention with WAVE-PAIRING (champion, verbatim).
// 16 waves/block on a 64-q tile; waves (2k,2k+1) share a j-range but handle
// different q-tiles -> pair issues identical K/V addresses, trailing wave
// hits L1.  Grid 256.  No-max exp2 softmax, zero cross-lane j-loop
// (j-permuted V^T), per-q-tile additive LDS merge, fused epilogue.
// ---------------------------------------------------------------------------
__global__ __launch_bounds__(1024)
void attn_kernel(const unsigned short* __restrict__ qt2,
                 const unsigned short* __restrict__ kt2,
                 const unsigned short* __restrict__ vt,
                 const float* __restrict__ x,
                 const float* __restrict__ gamma,
                 float* __restrict__ out)
{
    __shared__ float slds[4][64][64];   // merge slots [c][q 0..63], 64 KB
    __shared__ float sldl[4][64];       // l per slot

    const int t    = threadIdx.x;       // 0..1023
    const int l    = t & 63;
    const int wv   = t >> 6;            // 0..15
    const int qt   = wv & 1;            // q-tile of this wave (pairing key)
    const int u    = wv >> 1;           // 0..7 j-range id (shared by pair)
    const int lo31 = l & 31;
    const int h    = l >> 5;
    const int w     = blockIdx.x;
    const int b     = w >> 6;
    const int qbase = (w & 63) << 6;    // 64 q per block
    const int j0    = u << 9;           // 512 j per wave

    const unsigned short* qrow =
        qt2 + ((size_t)b * NTOK + qbase + qt * 32 + lo31) * 16;
    s16x8 qB1 = *(const s16x8*)qrow;
    s16x8 qB2;
    if (h == 0) qB2 = *(const s16x8*)(qrow + 8);
    else        { u32x4 z = {0,0,0,0}; qB2 = __builtin_bit_cast(s16x8, z); }

    const unsigned short* kb  = kt2 + (size_t)b * NTOK * 16 + (size_t)h * 8;
    const unsigned short* vbA = vt + (size_t)b * NTOK * 64 + (size_t)lo31 * 16 + 8 * h;
    const unsigned short* vbB = vbA + 512;

    f32x16 accA, accB;
    #pragma unroll
    for (int r = 0; r < 16; r++) { accA[r] = 0.f; accB[r] = 0.f; }
    float lsum = 0.f;

    s16x8 K[2], V00[2], V01[2], V10[2], V11[2];

    #define LOADSET(s_, a_) do {                                              \
        K[s_]   = *(const s16x8*)(kb + (size_t)(j0 + ((a_) << 5) + lo31) * 16);  \
        V00[s_] = *(const s16x8*)(vbA + (size_t)((j0 >> 4) + ((a_) << 1)) * 1024);     \
        V01[s_] = *(const s16x8*)(vbA + (size_t)((j0 >> 4) + ((a_) << 1) + 1) * 1024); \
        V10[s_] = *(const s16x8*)(vbB + (size_t)((j0 >> 4) + ((a_) << 1)) * 1024);     \
        V11[s_] = *(const s16x8*)(vbB + (size_t)((j0 >> 4) + ((a_) << 1) + 1) * 1024); \
    } while (0)

    LOADSET(0, 0);

    #pragma unroll
    for (int it = 0; it < 16; ++it) {
        const int cu = it & 1;
        const int nx = it + 1;
        LOADSET(cu ^ 1, (nx < 16) ? nx : 0);   // issue next-chunk loads first

        f32x16 s;
        #pragma unroll
        for (int r = 0; r < 16; r++) s[r] = 0.f;
        s = __builtin_amdgcn_mfma_f32_32x32x16_bf16(K[cu], qB1, s, 0, 0, 0);
        s = __builtin_amdgcn_mfma_f32_32x32x16_bf16(K[cu], qB2, s, 0, 0, 0);

        // ---- p = exp2(s) raw (no max needed: CQ=8 keeps |s| small) ----
        #pragma unroll
        for (int r = 0; r < 16; r++) s[r] = __builtin_amdgcn_exp2f(s[r]);

        lsum += ((s[0]+s[1])+(s[2]+s[3])) + ((s[4]+s[5])+(s[6]+s[7]))
              + ((s[8]+s[9])+(s[10]+s[11])) + ((s[12]+s[13])+(s[14]+s[15]));

        // ---- P^T -> B-frags: direct repack of own registers ----
        u32x4 wa, wc;
        wa.x = pk2(s[0], s[1]);   wa.y = pk2(s[2], s[3]);
        wa.z = pk2(s[4], s[5]);   wa.w = pk2(s[6], s[7]);
        wc.x = pk2(s[8], s[9]);   wc.y = pk2(s[10], s[11]);
        wc.z = pk2(s[12], s[13]); wc.w = pk2(s[14], s[15]);
        s16x8 pf0 = __builtin_bit_cast(s16x8, wa);
        s16x8 pf1 = __builtin_bit_cast(s16x8, wc);

        __builtin_amdgcn_s_setprio(1);
        accA = __builtin_amdgcn_mfma_f32_32x32x16_bf16(V00[cu], pf0, accA, 0, 0, 0);
        accA = __builtin_amdgcn_mfma_f32_32x32x16_bf16(V01[cu], pf1, accA, 0, 0, 0);
        accB = __builtin_amdgcn_mfma_f32_32x32x16_bf16(V10[cu], pf0, accB, 0, 0, 0);
        accB = __builtin_amdgcn_mfma_f32_32x32x16_bf16(V11[cu], pf1, accB, 0, 0, 0);
        __builtin_amdgcn_s_setprio(0);
    }

    lsum += __shfl_xor(lsum, 32);

    #define WR_SLOT(sidx) do {                                                \
        const int s_ = (sidx);                                                \
        _Pragma("unroll")                                                     \
        for (int r = 0; r < 16; r++) {                                        \
            const int c_ = (r & 3) + 8 * (r >> 2) + 4 * h;                    \
            slds[s_][c_][qt * 32 + lo31]      = accA[r];                      \
            slds[s_][c_ + 32][qt * 32 + lo31] = accB[r];                      \
        }                                                                     \
        if (h == 0) sldl[s_][qt * 32 + lo31] = lsum;                          \
    } while (0)

    #define MRG_SLOT(sidx) do {                                               \
        const int s_ = (sidx);                                                \
        _Pragma("unroll")                                                     \
        for (int r = 0; r < 16; r++) {                                        \
            const int c_ = (r & 3) + 8 * (r >> 2) + 4 * h;                    \
            accA[r] += slds[s_][c_][qt * 32 + lo31];                          \
            accB[r] += slds[s_][c_ + 32][qt * 32 + lo31];                     \
        }                                                                     \
        lsum += sldl[s_][qt * 32 + lo31];                                     \
    } while (0)

    if (u >= 4) WR_SLOT(u - 4);
    __syncthreads();
    if (u < 4) MRG_SLOT(u);
    __syncthreads();
    if (u == 2 || u == 3) WR_SLOT(u - 2);
    __syncthreads();
    if (u < 2) MRG_SLOT(u);
    __syncthreads();
    if (u == 1) WR_SLOT(0);
    __syncthreads();
    if (u == 0) { MRG_SLOT(0); WR_SLOT(0); }
    __syncthreads();

    // ---- fused epilogue: out = gamma*acc/L + x, all 1024 threads ----
    const int c  = t >> 4;              // 0..63
    const int q4 = (t & 15) << 2;       // 0,4,..,60
    const float g = gamma[0];
    const float4 a4 = *(const float4*)&slds[0][c][q4];
    const float g0 = g / sldl[0][q4 + 0];
    const float g1 = g / sldl[0][q4 + 1];
    const float g2 = g / sldl[0][q4 + 2];
    const float g3 = g / sldl[0][q4 + 3];
    const size_t off = (((size_t)b * 64 + c) << 12) + qbase + q4;
    const float4 xv4 = *(const float4*)(x + off);
    float4 o;
    o.x = a4.x * g0 + xv4.x;
    o.y = a4.y * g1 + xv4.y;
    o.z = a4.z * g2 + xv4.z;
    o.w = a4.w * g3 + xv4.w;
    *(float4*)(out + off) = o;
}

// ---------------------------------------------------------------------------
extern "C" void kernel_launch(void* const* d_in, const int* in_sizes, int n_in,
                              void* d_out, int out_size, void* d_ws, size_t ws_size,
                              hipStream_t stream) {
    const float* x     = (const float*)d_in[0];
    const float* Wq    = (const float*)d_in[1];
    const float* bq    = (const float*)d_in[2];
    const float* Wk    = (const float*)d_in[3];
    const float* bk    = (const float*)d_in[4];
    const float* Wv    = (const float*)d_in[5];
    const float* bv    = (const float*)d_in[6];
    const float* gamma = (const float*)d_in[7];
    float* out = (float*)d_out;

    unsigned short* qt2 = (unsigned short*)d_ws;            // 4*4096*16 bf16
    unsigned short* kt2 = qt2 + (size_t)4 * NTOK * 16;      // 4*4096*16 bf16
    unsigned short* vt  = kt2 + (size_t)4 * NTOK * 16;      // 4*4096*64 bf16 (tiled+permuted)

    qkv_kernel<<<128, 256, 0, stream>>>(x, Wq, bq, Wk, bk, Wv, bv, qt2, kt2, vt);
    attn_kernel<<<256, 1024, 0, stream>>>(qt2, kt2, vt, x, gamma, out);
}